// Round 1
// baseline (119.991 us; speedup 1.0000x reference)
//
#include <hip/hip_runtime.h>
#include <hip/hip_fp16.h>

#define T_CTX 100
#define C_DIM 384
#define H_DIM 64

typedef _Float16 half8   __attribute__((ext_vector_type(8)));
typedef _Float16 half4_t __attribute__((ext_vector_type(4)));
typedef float    f32x4   __attribute__((ext_vector_type(4)));

// ---- LDS layout (bytes) ----
// qs_h[128][72] @0, qs_l @18432, ks_h @36864, ks_l @55296          (fp16 planes)
// union @73728: phase1 xs (2 buf x 2 plane x 128*40 half = 40960 B)
//               phase2 vt[64][136] @73728 (17408), ps[128][136] @91136 (34816)
#define QS_H_OFF 0
#define QS_L_OFF 18432
#define KS_H_OFF 36864
#define KS_L_OFF 55296
#define XS_OFF   73728
#define VT_OFF   73728
#define PS_OFF   91136
#define SMEM_BYTES 125952

#define QS_STRIDE 72
#define XS_STRIDE 40
#define VT_STRIDE 136
#define PS_STRIDE 136

__global__ void prep_w_kernel(const float* __restrict__ Wq,
                              const float* __restrict__ Wk,
                              const float* __restrict__ Wv,
                              _Float16* __restrict__ wf_hi,
                              _Float16* __restrict__ wf_lo) {
    int idx = blockIdx.x * 256 + threadIdx.x;   // over 12*12*64 = 9216 frag-lanes
    if (idx >= 9216) return;
    int lane  = idx & 63;
    int chunk = (idx >> 6) % 12;
    int jt    = idx / (64 * 12);
    int col   = jt * 16 + (lane & 15);          // global N col 0..191 (q|k|v)
    const float* W = (col < 64) ? Wq : ((col < 128) ? Wk : Wv);
    int h = col & 63;
    int cbase = chunk * 32 + (lane >> 4) * 8;   // K index base
    #pragma unroll
    for (int e = 0; e < 8; ++e) {
        float f = W[(size_t)(cbase + e) * H_DIM + h];
        _Float16 hi = (_Float16)f;
        _Float16 lo = (_Float16)(f - (float)hi);
        size_t o = (size_t)idx * 8 + e;
        wf_hi[o] = hi;
        wf_lo[o] = lo;
    }
}

__global__ __launch_bounds__(512, 2)
void head_kernel(const float* __restrict__ x,
                 const _Float16* __restrict__ wf_hi,
                 const _Float16* __restrict__ wf_lo,
                 float* __restrict__ out) {
    extern __shared__ char smem[];
    _Float16* qs_h = (_Float16*)(smem + QS_H_OFF);
    _Float16* qs_l = (_Float16*)(smem + QS_L_OFF);
    _Float16* ks_h = (_Float16*)(smem + KS_H_OFF);
    _Float16* ks_l = (_Float16*)(smem + KS_L_OFF);
    _Float16* xs   = (_Float16*)(smem + XS_OFF);
    _Float16* vt   = (_Float16*)(smem + VT_OFF);
    _Float16* ps   = (_Float16*)(smem + PS_OFF);

    const int b    = blockIdx.x;
    const int tid  = threadIdx.x;
    const int lane = tid & 63;
    const int wid  = tid >> 6;      // 8 waves
    const int l15  = lane & 15;
    const int lg   = lane >> 4;     // 0..3
    const int mh   = wid >> 2;      // phase1: M half (rows mh*64..)
    const int nw   = wid & 3;       // phase1: N group (cols nw*48..)

    const float* xb = x + (size_t)b * T_CTX * C_DIM;

    // ================= phase 1: q,k,v = x @ W (fp16 hi/lo split, 3 products) =========
    f32x4 acc[4][3];
    #pragma unroll
    for (int i = 0; i < 4; ++i)
        #pragma unroll
        for (int j = 0; j < 3; ++j)
            acc[i][j] = (f32x4){0.f, 0.f, 0.f, 0.f};

    // prologue: stage chunk 0 into buffer 0
    #pragma unroll
    for (int s = 0; s < 2; ++s) {
        int f4  = tid + s * 512;
        int row = f4 >> 3;
        int c4  = f4 & 7;
        f32x4 v = (f32x4){0.f, 0.f, 0.f, 0.f};
        if (row < T_CTX) v = *(const f32x4*)(xb + row * C_DIM + c4 * 4);
        half4_t hh, ll;
        #pragma unroll
        for (int u = 0; u < 4; ++u) {
            _Float16 h = (_Float16)v[u];
            hh[u] = h;
            ll[u] = (_Float16)(v[u] - (float)h);
        }
        int o = row * XS_STRIDE + c4 * 4;
        *(half4_t*)(xs + o)        = hh;
        *(half4_t*)(xs + 5120 + o) = ll;
    }
    __syncthreads();

    for (int kc = 0; kc < 12; ++kc) {
        const int nk = kc + 1;
        f32x4 ld[2];
        if (nk < 12) {                       // issue next-chunk global loads early
            #pragma unroll
            for (int s = 0; s < 2; ++s) {
                int f4  = tid + s * 512;
                int row = f4 >> 3;
                int c4  = f4 & 7;
                ld[s] = (f32x4){0.f, 0.f, 0.f, 0.f};
                if (row < T_CTX) ld[s] = *(const f32x4*)(xb + row * C_DIM + nk * 32 + c4 * 4);
            }
        }
        const _Float16* xh = xs + (kc & 1) * 10240;
        const _Float16* xl = xh + 5120;
        half8 ah[4], al[4];
        #pragma unroll
        for (int i = 0; i < 4; ++i) {
            int o = (mh * 64 + i * 16 + l15) * XS_STRIDE + lg * 8;
            ah[i] = *(const half8*)(xh + o);
            al[i] = *(const half8*)(xl + o);
        }
        #pragma unroll
        for (int jj = 0; jj < 3; ++jj) {
            size_t o = ((size_t)((nw * 3 + jj) * 12 + kc) * 64 + lane) * 8;
            half8 bh = *(const half8*)(wf_hi + o);
            half8 bl = *(const half8*)(wf_lo + o);
            #pragma unroll
            for (int i = 0; i < 4; ++i) {
                acc[i][jj] = __builtin_amdgcn_mfma_f32_16x16x32_f16(ah[i], bh, acc[i][jj], 0, 0, 0);
                acc[i][jj] = __builtin_amdgcn_mfma_f32_16x16x32_f16(al[i], bh, acc[i][jj], 0, 0, 0);
                acc[i][jj] = __builtin_amdgcn_mfma_f32_16x16x32_f16(ah[i], bl, acc[i][jj], 0, 0, 0);
            }
        }
        if (nk < 12) {                       // write next chunk into the other buffer
            #pragma unroll
            for (int s = 0; s < 2; ++s) {
                int f4  = tid + s * 512;
                int row = f4 >> 3;
                int c4  = f4 & 7;
                half4_t hh, ll;
                #pragma unroll
                for (int u = 0; u < 4; ++u) {
                    _Float16 h = (_Float16)ld[s][u];
                    hh[u] = h;
                    ll[u] = (_Float16)(ld[s][u] - (float)h);
                }
                int o = row * XS_STRIDE + c4 * 4;
                *(half4_t*)(xs + (nk & 1) * 10240 + o)        = hh;
                *(half4_t*)(xs + (nk & 1) * 10240 + 5120 + o) = ll;
            }
        }
        __syncthreads();
    }

    // epilogue: q,k -> hi/lo planes; v -> transposed fp16 (xs is dead now)
    #pragma unroll
    for (int i = 0; i < 4; ++i) {
        #pragma unroll
        for (int jj = 0; jj < 3; ++jj) {
            int ncol  = nw * 48 + jj * 16 + l15;
            int rbase = mh * 64 + i * 16 + lg * 4;
            #pragma unroll
            for (int r = 0; r < 4; ++r) {
                float v = acc[i][jj][r];
                int row = rbase + r;
                if (ncol < 64) {
                    _Float16 h = (_Float16)v;
                    qs_h[row * QS_STRIDE + ncol] = h;
                    qs_l[row * QS_STRIDE + ncol] = (_Float16)(v - (float)h);
                } else if (ncol < 128) {
                    int hc = ncol - 64;
                    _Float16 h = (_Float16)v;
                    ks_h[row * QS_STRIDE + hc] = h;
                    ks_l[row * QS_STRIDE + hc] = (_Float16)(v - (float)h);
                } else {
                    vt[(ncol - 128) * VT_STRIDE + row] = (_Float16)v;
                }
            }
        }
    }
    __syncthreads();

    // ================= phase 2: scores (split fp16), softmax ==========================
    f32x4 sacc[7];
    #pragma unroll
    for (int j = 0; j < 7; ++j) sacc[j] = (f32x4){0.f, 0.f, 0.f, 0.f};

    {
        const int qrow = wid * 16 + l15;          // A-frag row
        #pragma unroll
        for (int kk = 0; kk < 2; ++kk) {
            int qo = qrow * QS_STRIDE + kk * 32 + lg * 8;
            half8 qh = *(const half8*)(qs_h + qo);
            half8 ql = *(const half8*)(qs_l + qo);
            #pragma unroll
            for (int j = 0; j < 7; ++j) {
                int ko = (j * 16 + l15) * QS_STRIDE + kk * 32 + lg * 8;  // B-frag col=key
                half8 kh = *(const half8*)(ks_h + ko);
                half8 kl = *(const half8*)(ks_l + ko);
                sacc[j] = __builtin_amdgcn_mfma_f32_16x16x32_f16(qh, kh, sacc[j], 0, 0, 0);
                sacc[j] = __builtin_amdgcn_mfma_f32_16x16x32_f16(ql, kh, sacc[j], 0, 0, 0);
                sacc[j] = __builtin_amdgcn_mfma_f32_16x16x32_f16(qh, kl, sacc[j], 0, 0, 0);
            }
        }
    }

    float rmax[4] = {-1e30f, -1e30f, -1e30f, -1e30f};
    float sv[7][4];
    #pragma unroll
    for (int j = 0; j < 7; ++j) {
        int key = j * 16 + l15;
        #pragma unroll
        for (int r = 0; r < 4; ++r) {
            int row = wid * 16 + lg * 4 + r;
            // faithful bug: multiply by sqrt(64)=8; causal + key<100 mask
            float s = (key <= row && key < T_CTX) ? sacc[j][r] * 8.0f : -1e30f;
            sv[j][r] = s;
            rmax[r] = fmaxf(rmax[r], s);
        }
    }
    #pragma unroll
    for (int r = 0; r < 4; ++r) {
        #pragma unroll
        for (int d = 1; d < 16; d <<= 1)
            rmax[r] = fmaxf(rmax[r], __shfl_xor(rmax[r], d, 64));
    }
    float rsum[4] = {0.f, 0.f, 0.f, 0.f};
    #pragma unroll
    for (int j = 0; j < 7; ++j) {
        #pragma unroll
        for (int r = 0; r < 4; ++r) {
            float p = __expf(sv[j][r] - rmax[r]);   // masked -> exp(-1e30) == 0
            rsum[r] += p;
            ps[(wid * 16 + lg * 4 + r) * PS_STRIDE + j * 16 + l15] = (_Float16)p;
        }
    }
    #pragma unroll
    for (int r = 0; r < 4; ++r) {
        ps[(wid * 16 + lg * 4 + r) * PS_STRIDE + 112 + l15] = (_Float16)0.f; // pad keys
        #pragma unroll
        for (int d = 1; d < 16; d <<= 1)
            rsum[r] += __shfl_xor(rsum[r], d, 64);
    }
    __syncthreads();

    // ================= phase 3: out = (P @ V) / rowsum ================================
    f32x4 oacc[4];
    #pragma unroll
    for (int j = 0; j < 4; ++j) oacc[j] = (f32x4){0.f, 0.f, 0.f, 0.f};
    const int prow = wid * 16 + l15;
    #pragma unroll
    for (int kk = 0; kk < 4; ++kk) {
        half8 pa = *(const half8*)(ps + prow * PS_STRIDE + kk * 32 + lg * 8);
        #pragma unroll
        for (int jh = 0; jh < 4; ++jh) {
            half8 vb = *(const half8*)(vt + (jh * 16 + l15) * VT_STRIDE + kk * 32 + lg * 8);
            oacc[jh] = __builtin_amdgcn_mfma_f32_16x16x32_f16(pa, vb, oacc[jh], 0, 0, 0);
        }
    }
    #pragma unroll
    for (int jh = 0; jh < 4; ++jh) {
        #pragma unroll
        for (int r = 0; r < 4; ++r) {
            int t = wid * 16 + lg * 4 + r;
            if (t < T_CTX)
                out[((size_t)b * T_CTX + t) * H_DIM + jh * 16 + l15] = oacc[jh][r] / rsum[r];
        }
    }
}

extern "C" void kernel_launch(void* const* d_in, const int* in_sizes, int n_in,
                              void* d_out, int out_size, void* d_ws, size_t ws_size,
                              hipStream_t stream) {
    const float* x  = (const float*)d_in[0];
    const float* Wq = (const float*)d_in[1];
    const float* Wk = (const float*)d_in[2];
    const float* Wv = (const float*)d_in[3];

    _Float16* wf_hi = (_Float16*)d_ws;                 // 12*12*64*8 halfs = 147456 B
    _Float16* wf_lo = wf_hi + (size_t)9216 * 8;        // total ws use: 294912 B

    prep_w_kernel<<<36, 256, 0, stream>>>(Wq, Wk, Wv, wf_hi, wf_lo);

    (void)hipFuncSetAttribute((const void*)head_kernel,
                              hipFuncAttributeMaxDynamicSharedMemorySize, SMEM_BYTES);
    head_kernel<<<1024, 512, SMEM_BYTES, stream>>>(x, wf_hi, wf_lo, (float*)d_out);
}

// Round 2
// 77.391 us; speedup vs baseline: 1.5505x; 1.5505x over previous
//
#include <hip/hip_runtime.h>
#include <hip/hip_fp16.h>

#define T_CTX 100
#define C_DIM 384
#define H_DIM 64

typedef _Float16 half8   __attribute__((ext_vector_type(8)));
typedef _Float16 half4_t __attribute__((ext_vector_type(4)));
typedef float    f32x4   __attribute__((ext_vector_type(4)));

// ---- LDS layout, units = halfs (2B) ----
// Persistent (phase2/3):
//   QH [8 waves][2 kk][64 lane][8]  @ 0      (8192 halfs)
//   QL                              @ 8192   (8192)
//   KH [7 keytile][2 kk][64][8]     @ 16384  (7168)
//   KL                              @ 23552  (7168)
//   VT [4 jh][4 kk][64][8]          @ 30720  (8192)
//   total = 38912 halfs = 77824 B  -> 2 blocks/CU (160 KB LDS)
// Overlays:
//   XS (phase1 staging, dead at epilogue): 2 buf x (hi@0,lo@5120) x 128x40  @ 0 (20480 halfs)
//   PS [8 waves][4 kk][64][8] (written after q/k dead)                      @ 0 (16384 halfs)
#define QH_OFF 0
#define QL_OFF 8192
#define KH_OFF 16384
#define KL_OFF 23552
#define VT_OFF 30720
#define XS_OFF 0
#define PS_OFF 0
#define SMEM_BYTES 77824

__global__ void prep_w_kernel(const float* __restrict__ Wq,
                              const float* __restrict__ Wk,
                              const float* __restrict__ Wv,
                              _Float16* __restrict__ wf_hi,
                              _Float16* __restrict__ wf_lo) {
    int idx = blockIdx.x * 256 + threadIdx.x;   // over 12*12*64 = 9216 frag-lanes
    if (idx >= 9216) return;
    int lane  = idx & 63;
    int chunk = (idx >> 6) % 12;
    int jt    = idx / (64 * 12);
    int col   = jt * 16 + (lane & 15);          // global N col 0..191 (q|k|v)
    const float* W = (col < 64) ? Wq : ((col < 128) ? Wk : Wv);
    int h = col & 63;
    int cbase = chunk * 32 + (lane >> 4) * 8;   // K index base
    #pragma unroll
    for (int e = 0; e < 8; ++e) {
        float f = W[(size_t)(cbase + e) * H_DIM + h];
        _Float16 hi = (_Float16)f;
        _Float16 lo = (_Float16)(f - (float)hi);
        size_t o = (size_t)idx * 8 + e;
        wf_hi[o] = hi;
        wf_lo[o] = lo;
    }
}

__global__ __launch_bounds__(512, 4)
void head_kernel(const float* __restrict__ x,
                 const _Float16* __restrict__ wf_hi,
                 const _Float16* __restrict__ wf_lo,
                 float* __restrict__ out) {
    extern __shared__ _Float16 sm[];

    const int b    = blockIdx.x;
    const int tid  = threadIdx.x;
    const int lane = tid & 63;
    const int wid  = tid >> 6;      // 8 waves
    const int l15  = lane & 15;
    const int lg   = lane >> 4;     // 0..3
    const int mh   = wid >> 2;      // phase1: M half (rows mh*64..)
    const int nw   = wid & 3;       // phase1: N group (cols nw*48..)

    const float* xb = x + (size_t)b * T_CTX * C_DIM;
    _Float16* xs = sm + XS_OFF;

    // ================= phase 1: q,k,v = x @ W (fp16 hi/lo split, 3 products) =========
    f32x4 acc[4][3];
    #pragma unroll
    for (int i = 0; i < 4; ++i)
        #pragma unroll
        for (int j = 0; j < 3; ++j)
            acc[i][j] = (f32x4){0.f, 0.f, 0.f, 0.f};

    // prologue: stage chunk 0 into buffer 0 (rows >= T_CTX zero-filled)
    #pragma unroll
    for (int s = 0; s < 2; ++s) {
        int f4  = tid + s * 512;
        int row = f4 >> 3;
        int c4  = f4 & 7;
        f32x4 v = (f32x4){0.f, 0.f, 0.f, 0.f};
        if (row < T_CTX) v = *(const f32x4*)(xb + row * C_DIM + c4 * 4);
        half4_t hh, ll;
        #pragma unroll
        for (int u = 0; u < 4; ++u) {
            _Float16 h = (_Float16)v[u];
            hh[u] = h;
            ll[u] = (_Float16)(v[u] - (float)h);
        }
        int o = row * 40 + c4 * 4;
        *(half4_t*)(xs + o)        = hh;
        *(half4_t*)(xs + 5120 + o) = ll;
    }
    __syncthreads();

    for (int kc = 0; kc < 12; ++kc) {
        const int nk = kc + 1;
        f32x4 ld[2];
        if (nk < 12) {                       // issue next-chunk global loads early
            #pragma unroll
            for (int s = 0; s < 2; ++s) {
                int f4  = tid + s * 512;
                int row = f4 >> 3;
                int c4  = f4 & 7;
                ld[s] = (f32x4){0.f, 0.f, 0.f, 0.f};
                if (row < T_CTX) ld[s] = *(const f32x4*)(xb + row * C_DIM + nk * 32 + c4 * 4);
            }
        }
        const _Float16* xh = xs + (kc & 1) * 10240;
        const _Float16* xl = xh + 5120;
        half8 ah[4], al[4];
        #pragma unroll
        for (int i = 0; i < 4; ++i) {
            int o = (mh * 64 + i * 16 + l15) * 40 + lg * 8;
            ah[i] = *(const half8*)(xh + o);
            al[i] = *(const half8*)(xl + o);
        }
        #pragma unroll
        for (int jj = 0; jj < 3; ++jj) {
            size_t o = ((size_t)((nw * 3 + jj) * 12 + kc) * 64 + lane) * 8;
            half8 bh = *(const half8*)(wf_hi + o);
            half8 bl = *(const half8*)(wf_lo + o);
            #pragma unroll
            for (int i = 0; i < 4; ++i) {
                acc[i][jj] = __builtin_amdgcn_mfma_f32_16x16x32_f16(ah[i], bh, acc[i][jj], 0, 0, 0);
                acc[i][jj] = __builtin_amdgcn_mfma_f32_16x16x32_f16(al[i], bh, acc[i][jj], 0, 0, 0);
                acc[i][jj] = __builtin_amdgcn_mfma_f32_16x16x32_f16(ah[i], bl, acc[i][jj], 0, 0, 0);
            }
        }
        if (nk < 12) {                       // write next chunk into the other buffer
            #pragma unroll
            for (int s = 0; s < 2; ++s) {
                int f4  = tid + s * 512;
                int row = f4 >> 3;
                int c4  = f4 & 7;
                half4_t hh, ll;
                #pragma unroll
                for (int u = 0; u < 4; ++u) {
                    _Float16 h = (_Float16)ld[s][u];
                    hh[u] = h;
                    ll[u] = (_Float16)(ld[s][u] - (float)h);
                }
                int o = row * 40 + c4 * 4;
                *(half4_t*)(xs + (nk & 1) * 10240 + o)        = hh;
                *(half4_t*)(xs + (nk & 1) * 10240 + 5120 + o) = ll;
            }
        }
        __syncthreads();
    }

    // epilogue: scatter q,k (hi/lo) and v into fragment-packed LDS (xs is dead)
    #pragma unroll
    for (int i = 0; i < 4; ++i) {
        #pragma unroll
        for (int jj = 0; jj < 3; ++jj) {
            int ncol = nw * 48 + jj * 16 + l15;
            #pragma unroll
            for (int r = 0; r < 4; ++r) {
                int row = mh * 64 + i * 16 + lg * 4 + r;   // time index t (0..127)
                float val = acc[i][jj][r];
                if (ncol < 64) {
                    // q[t][h=ncol] -> A-frag packed: [tile t/16][kk][lgd*16 + t%16][e]
                    int off = (row >> 4) * 1024 + (ncol >> 5) * 512
                            + (((ncol >> 3) & 3) * 16 + (row & 15)) * 8 + (ncol & 7);
                    _Float16 h = (_Float16)val;
                    sm[QH_OFF + off] = h;
                    sm[QL_OFF + off] = (_Float16)(val - (float)h);
                } else if (ncol < 128) {
                    // k[t][h] -> B-frag packed: [tile t/16][kk(h/32)][lgd*16 + t%16][e]
                    if (row < 112) {
                        int hc = ncol - 64;
                        int off = (row >> 4) * 1024 + (hc >> 5) * 512
                                + (((hc >> 3) & 3) * 16 + (row & 15)) * 8 + (hc & 7);
                        _Float16 h = (_Float16)val;
                        sm[KH_OFF + off] = h;
                        sm[KL_OFF + off] = (_Float16)(val - (float)h);
                    }
                } else {
                    // v[t][h] -> B-frag packed for PV: [jh(h/16)][kk(t/32)][lgd(t)*16 + h%16][e(t)]
                    int hc = ncol - 128;
                    int off = (hc >> 4) * 2048 + (row >> 5) * 512
                            + (((row >> 3) & 3) * 16 + (hc & 15)) * 8 + (row & 7);
                    sm[VT_OFF + off] = (_Float16)val;
                }
            }
        }
    }
    __syncthreads();

    // ================= phase 2: scores (split fp16), softmax ==========================
    f32x4 sacc[7];
    #pragma unroll
    for (int j = 0; j < 7; ++j) sacc[j] = (f32x4){0.f, 0.f, 0.f, 0.f};

    #pragma unroll
    for (int kk = 0; kk < 2; ++kk) {
        half8 qh = *(const half8*)(sm + QH_OFF + wid * 1024 + kk * 512 + lane * 8);
        half8 ql = *(const half8*)(sm + QL_OFF + wid * 1024 + kk * 512 + lane * 8);
        #pragma unroll
        for (int j = 0; j < 7; ++j) {
            half8 kh = *(const half8*)(sm + KH_OFF + j * 1024 + kk * 512 + lane * 8);
            half8 kl = *(const half8*)(sm + KL_OFF + j * 1024 + kk * 512 + lane * 8);
            sacc[j] = __builtin_amdgcn_mfma_f32_16x16x32_f16(qh, kh, sacc[j], 0, 0, 0);
            sacc[j] = __builtin_amdgcn_mfma_f32_16x16x32_f16(ql, kh, sacc[j], 0, 0, 0);
            sacc[j] = __builtin_amdgcn_mfma_f32_16x16x32_f16(qh, kl, sacc[j], 0, 0, 0);
        }
    }

    float rmax[4] = {-1e30f, -1e30f, -1e30f, -1e30f};
    float sv[7][4];
    #pragma unroll
    for (int j = 0; j < 7; ++j) {
        int key = j * 16 + l15;
        #pragma unroll
        for (int r = 0; r < 4; ++r) {
            int row = wid * 16 + lg * 4 + r;
            // faithful bug: multiply by sqrt(64)=8; causal + key<100 mask
            float s = (key <= row && key < T_CTX) ? sacc[j][r] * 8.0f : -1e30f;
            sv[j][r] = s;
            rmax[r] = fmaxf(rmax[r], s);
        }
    }
    #pragma unroll
    for (int r = 0; r < 4; ++r) {
        #pragma unroll
        for (int d = 1; d < 16; d <<= 1)
            rmax[r] = fmaxf(rmax[r], __shfl_xor(rmax[r], d, 64));
    }

    __syncthreads();   // all waves done reading q/k before PS overlays that region

    float rsum[4] = {0.f, 0.f, 0.f, 0.f};
    #pragma unroll
    for (int j = 0; j < 7; ++j) {
        int key = j * 16 + l15;
        #pragma unroll
        for (int r = 0; r < 4; ++r) {
            float p = __expf(sv[j][r] - rmax[r]);   // masked -> 0
            rsum[r] += p;
            int a = lg * 4 + r;                     // q-row within wave tile
            int off = wid * 2048 + (key >> 5) * 512
                    + (((key >> 3) & 3) * 16 + a) * 8 + (key & 7);
            sm[PS_OFF + off] = (_Float16)p;
        }
    }
    #pragma unroll
    for (int r = 0; r < 4; ++r) {                   // zero pad keys 112..127
        int key = 112 + l15;
        int a = lg * 4 + r;
        int off = wid * 2048 + (key >> 5) * 512
                + (((key >> 3) & 3) * 16 + a) * 8 + (key & 7);
        sm[PS_OFF + off] = (_Float16)0.f;
        #pragma unroll
        for (int d = 1; d < 16; d <<= 1)
            rsum[r] += __shfl_xor(rsum[r], d, 64);
    }
    __syncthreads();

    // ================= phase 3: out = (P @ V) / rowsum ================================
    f32x4 oacc[4];
    #pragma unroll
    for (int j = 0; j < 4; ++j) oacc[j] = (f32x4){0.f, 0.f, 0.f, 0.f};
    #pragma unroll
    for (int kk = 0; kk < 4; ++kk) {
        half8 pa = *(const half8*)(sm + PS_OFF + wid * 2048 + kk * 512 + lane * 8);
        #pragma unroll
        for (int jh = 0; jh < 4; ++jh) {
            half8 vb = *(const half8*)(sm + VT_OFF + jh * 2048 + kk * 512 + lane * 8);
            oacc[jh] = __builtin_amdgcn_mfma_f32_16x16x32_f16(pa, vb, oacc[jh], 0, 0, 0);
        }
    }
    #pragma unroll
    for (int jh = 0; jh < 4; ++jh) {
        #pragma unroll
        for (int r = 0; r < 4; ++r) {
            int t = wid * 16 + lg * 4 + r;
            if (t < T_CTX)
                out[((size_t)b * T_CTX + t) * H_DIM + jh * 16 + l15] = oacc[jh][r] / rsum[r];
        }
    }
}

extern "C" void kernel_launch(void* const* d_in, const int* in_sizes, int n_in,
                              void* d_out, int out_size, void* d_ws, size_t ws_size,
                              hipStream_t stream) {
    const float* x  = (const float*)d_in[0];
    const float* Wq = (const float*)d_in[1];
    const float* Wk = (const float*)d_in[2];
    const float* Wv = (const float*)d_in[3];

    _Float16* wf_hi = (_Float16*)d_ws;                 // 12*12*64*8 halfs = 147456 B
    _Float16* wf_lo = wf_hi + (size_t)9216 * 8;        // total ws use: 294912 B

    prep_w_kernel<<<36, 256, 0, stream>>>(Wq, Wk, Wv, wf_hi, wf_lo);

    (void)hipFuncSetAttribute((const void*)head_kernel,
                              hipFuncAttributeMaxDynamicSharedMemorySize, SMEM_BYTES);
    head_kernel<<<1024, 512, SMEM_BYTES, stream>>>(x, wf_hi, wf_lo, (float*)d_out);
}